// Round 5
// baseline (607.659 us; speedup 1.0000x reference)
//
#include <hip/hip_runtime.h>

// VQ-VAE codebook quantization — 3-kernel: fp32 screen + fp64 repair + writer.
// x: (4096, 1024) f32; codebook: (128, 256, 8) f32.
// out = [cw_embed (4096*1024 f32) | one_hot (4096*128*256 f32)].
//
// R4 post-mortem: the screen is LDS-issue-bound (768 ds_read per thread,
// ~51 us chip-wide at BPT=2), which is why fp64->fp32 barely moved. This
// round: BPT=8 amortizes the LDS reads 4x (-> ~13 us LDS, ~22 us VALU floor).
// Writer already streams at fill-rate (~95 us for 554 MB); fp64 repair ~10 us.
// Remaining dur_us is dominated by a fixed harness poison-fill component
// (~450 us of 2.2GB fillBuffer dispatches visible in rocprof).

constexpr int B_  = 4096;
constexpr int C_  = 128;
constexpr int K_  = 256;
constexpr int D_  = 8;
constexpr int TPB = 256;
constexpr int NP  = B_ * C_;   // 524288 pairs

typedef float vf4 __attribute__((ext_vector_type(4)));

// ---------------- Pass 1: fp32 top-2 screen ----------------
constexpr int   BPT1   = 8;            // b's per thread (amortize LDS reads)
constexpr int   BTILE1 = TPB * BPT1;   // 2048 b per block
constexpr float TAU2   = 1.0e-3f;      // ambiguity gap threshold (2*tau)

__global__ __launch_bounds__(TPB) void vq_screen(
    const float* __restrict__ x,
    const float* __restrict__ cb,
    int* __restrict__ idx_out)
{
    __shared__ float s_cbf[K_ * D_];  // 8 KB fp32 codebook slice
    __shared__ float s_c2f[K_];       // 1 KB fp32 ||c_k||^2

    const int c     = blockIdx.x;  // 0..127
    const int btile = blockIdx.y;  // 0..1
    const int tid   = threadIdx.x;

    {
        const float4* gcb = (const float4*)(cb + (size_t)c * (K_ * D_));
        ((float4*)s_cbf)[tid]       = gcb[tid];
        ((float4*)s_cbf)[tid + TPB] = gcb[tid + TPB];
    }
    __syncthreads();
    {
        const float* v = s_cbf + tid * D_;
        float s = 0.f;
        #pragma unroll
        for (int d = 0; d < D_; ++d) s = fmaf(v[d], v[d], s);
        s_c2f[tid] = s;
    }
    __syncthreads();

    float xf[BPT1][D_];
    #pragma unroll
    for (int j = 0; j < BPT1; ++j) {
        const int b = btile * BTILE1 + j * TPB + tid;
        const float4* xp = (const float4*)(x + (size_t)b * (C_ * D_) + c * D_);
        const float4 a = xp[0];
        const float4 h = xp[1];
        xf[j][0] = a.x; xf[j][1] = a.y; xf[j][2] = a.z; xf[j][3] = a.w;
        xf[j][4] = h.x; xf[j][5] = h.y; xf[j][6] = h.z; xf[j][7] = h.w;
    }

    float s1[BPT1], s2[BPT1];
    int   k1[BPT1];
    #pragma unroll
    for (int j = 0; j < BPT1; ++j) { s1[j] = 3.4e38f; s2[j] = 3.4e38f; k1[j] = 0; }

    const float4* scb4 = (const float4*)s_cbf;
    #pragma unroll 2
    for (int k = 0; k < K_; ++k) {
        const float4 clo = scb4[k * 2];
        const float4 chi = scb4[k * 2 + 1];
        const float  c2k = s_c2f[k];
        #pragma unroll
        for (int j = 0; j < BPT1; ++j) {
            float dot = xf[j][0] * clo.x;
            dot = fmaf(xf[j][1], clo.y, dot);
            dot = fmaf(xf[j][2], clo.z, dot);
            dot = fmaf(xf[j][3], clo.w, dot);
            dot = fmaf(xf[j][4], chi.x, dot);
            dot = fmaf(xf[j][5], chi.y, dot);
            dot = fmaf(xf[j][6], chi.z, dot);
            dot = fmaf(xf[j][7], chi.w, dot);
            const float score = fmaf(-2.f, dot, c2k);
            // top-2 (s2 uses OLD s1; strict < keeps first-index winner)
            s2[j] = fminf(s2[j], fmaxf(score, s1[j]));
            const bool lt = score < s1[j];
            k1[j] = lt ? k : k1[j];
            s1[j] = lt ? score : s1[j];
        }
    }

    #pragma unroll
    for (int j = 0; j < BPT1; ++j) {
        const int b = btile * BTILE1 + j * TPB + tid;
        const bool amb = (s2[j] - s1[j]) <= TAU2;  // fp64 could reorder -> flag
        idx_out[(size_t)b * C_ + c] = k1[j] | (amb ? (1 << 31) : 0);
    }
}

// ---------------- Pass 2: fp64 repair of flagged pairs ----------------
// One full wave per flagged pair: 4 codes/lane in fp64 (exact formula that
// scored absmax 0.0 in R2-R4), first-index tie-break.
constexpr int FIXBLKS = 256;

__global__ __launch_bounds__(TPB, 4) void vq_fix(
    const float* __restrict__ x,
    const float* __restrict__ cb,
    int* __restrict__ idx)
{
    const int lane   = threadIdx.x & 63;
    const int gwave  = (blockIdx.x * TPB + threadIdx.x) >> 6;
    const int nwaves = (FIXBLKS * TPB) >> 6;  // 1024

    for (int base = gwave * 64; base < NP; base += nwaves * 64) {
        const int v = idx[base + lane];
        unsigned long long mask = __ballot(v < 0);
        while (mask) {
            const int src = (int)__ffsll((long long)mask) - 1;
            mask &= mask - 1;
            const int pair = base + src;
            const int b = pair >> 7;        // /C_
            const int c = pair & (C_ - 1);

            const float* xp = x  + (size_t)b * (C_ * D_) + c * D_;
            const float* cp = cb + (size_t)c * (K_ * D_);

            double xd[D_];
            #pragma unroll
            for (int d = 0; d < D_; ++d) xd[d] = (double)xp[d];

            double best = 1.0e300;
            int    bk   = 0;
            #pragma unroll
            for (int t = 0; t < 4; ++t) {
                const int k = lane * 4 + t;   // ascending k within lane
                const float* cv = cp + k * D_;
                double cd[D_];
                #pragma unroll
                for (int d = 0; d < D_; ++d) cd[d] = (double)cv[d];
                double c2k = 0.0;
                #pragma unroll
                for (int d = 0; d < D_; ++d) c2k = fma(cd[d], cd[d], c2k);
                double dot = xd[0] * cd[0];
                #pragma unroll
                for (int d = 1; d < D_; ++d) dot = fma(xd[d], cd[d], dot);
                const double score = fma(-2.0, dot, c2k);
                if (score < best) { best = score; bk = k; }  // first-min
            }
            // reduce: strictly smaller wins; tie -> lower lane (= lower k)
            #pragma unroll
            for (int off = 32; off >= 1; off >>= 1) {
                const double ob  = __shfl_down(best, off);
                const int    obk = __shfl_down(bk,   off);
                if (ob < best) { best = ob; bk = obk; }
            }
            if (lane == 0) idx[pair] = bk;   // clears bit31 too
        }
    }
}

// ---------------- Pass 3: coalesced streaming writer ----------------
constexpr int GRID3 = 2048;
constexpr int RPB   = NP / GRID3;  // 256 rows per block

__global__ __launch_bounds__(TPB, 4) void vq_write(
    const int*   __restrict__ idx,
    const float* __restrict__ cb,
    float* __restrict__ out_embed,
    float* __restrict__ out_onehot)
{
    const int tid  = threadIdx.x;
    const int lane = tid & 63;
    const int wave = tid >> 6;
    const int blk  = blockIdx.x;

    // one-hot: 64 consecutive rows per wave, 1KB contiguous per store instr
    const int rowbase = blk * RPB + wave * 64;
    const int myk = idx[rowbase + lane];
    const int e0 = lane * 4;
    #pragma unroll 4
    for (int i = 0; i < 64; ++i) {
        const int k = __builtin_amdgcn_readlane(myk, i);
        vf4 v;
        v.x = (k == e0    ) ? 1.f : 0.f;
        v.y = (k == e0 + 1) ? 1.f : 0.f;
        v.z = (k == e0 + 2) ? 1.f : 0.f;
        v.w = (k == e0 + 3) ? 1.f : 0.f;
        vf4* dst = (vf4*)(out_onehot + (size_t)(rowbase + i) * K_) + lane;
        __builtin_nontemporal_store(v, dst);
    }

    // embed: 256 pairs per block = 512 float4, 2 per thread, coalesced
    const size_t pbase = (size_t)blk * RPB;
    #pragma unroll
    for (int i = 0; i < 2; ++i) {
        const int    f    = i * TPB + tid;   // 0..511
        const int    pl   = f >> 1;
        const int    half = f & 1;
        const size_t pair = pbase + pl;
        const int    c    = (int)(pair & (C_ - 1));
        const int    k    = idx[pair];
        const vf4 val = ((const vf4*)(cb + ((size_t)c * K_ + k) * D_))[half];
        __builtin_nontemporal_store(val, (vf4*)(out_embed + pbase * D_) + f);
    }
}

extern "C" void kernel_launch(void* const* d_in, const int* in_sizes, int n_in,
                              void* d_out, int out_size, void* d_ws, size_t ws_size,
                              hipStream_t stream) {
    const float* x  = (const float*)d_in[0];
    const float* cb = (const float*)d_in[1];
    float* out        = (float*)d_out;
    float* out_embed  = out;                          // 4096*1024
    float* out_onehot = out + (size_t)B_ * C_ * D_;   // 4096*128*256
    int*   idx_ws     = (int*)d_ws;                   // 524288 ints = 2 MB

    dim3 grid1(C_, B_ / BTILE1);  // (128, 2) = 256 blocks
    vq_screen<<<grid1, TPB, 0, stream>>>(x, cb, idx_ws);

    vq_fix<<<FIXBLKS, TPB, 0, stream>>>(x, cb, idx_ws);

    vq_write<<<GRID3, TPB, 0, stream>>>(idx_ws, cb, out_embed, out_onehot);
}

// Round 6
// 602.217 us; speedup vs baseline: 1.0090x; 1.0090x over previous
//
#include <hip/hip_runtime.h>

// VQ-VAE codebook quantization — 2-kernel: fused fp32-screen+fp64-repair, writer.
// x: (4096, 1024) f32; codebook: (128, 256, 8) f32.
// out = [cw_embed (4096*1024 f32) | one_hot (4096*128*256 f32)].
//
// R5 post-mortem: screen-cost changes (fp64->fp32, BPT 2->8) never moved
// dur_us => screen isn't the critical term. Unaccounted ~100us pinned on
// vq_fix (flagged-fraction unvalidated; wave-serial fp64 re-eval w/ global
// gathers). This round: repair ambiguous pairs INLINE in the screen block —
// wave-cooperative, x broadcast from regs via shfl, codes from the
// LDS-resident slice (f32->f64 convert == R2's exact staging). One dispatch
// less, zero extra global traffic. Writer byte-identical to R5.

constexpr int B_  = 4096;
constexpr int C_  = 128;
constexpr int K_  = 256;
constexpr int D_  = 8;
constexpr int TPB = 256;
constexpr int NP  = B_ * C_;   // 524288 pairs

typedef float vf4 __attribute__((ext_vector_type(4)));

// ---------------- Pass 1: fp32 top-2 screen + inline fp64 repair ----------------
constexpr int   BPT1   = 8;            // b's per thread
constexpr int   BTILE1 = TPB * BPT1;   // 2048 b per block
constexpr float TAU2   = 1.0e-3f;      // ambiguity gap threshold (2*tau)

__global__ __launch_bounds__(TPB) void vq_screen_fix(
    const float* __restrict__ x,
    const float* __restrict__ cb,
    int* __restrict__ idx_out)
{
    __shared__ float s_cbf[K_ * D_];  // 8 KB fp32 codebook slice
    __shared__ float s_c2f[K_];       // 1 KB fp32 ||c_k||^2

    const int c     = blockIdx.x;  // 0..127
    const int btile = blockIdx.y;  // 0..1
    const int tid   = threadIdx.x;
    const int lane  = tid & 63;

    {
        const float4* gcb = (const float4*)(cb + (size_t)c * (K_ * D_));
        ((float4*)s_cbf)[tid]       = gcb[tid];
        ((float4*)s_cbf)[tid + TPB] = gcb[tid + TPB];
    }
    __syncthreads();
    {
        const float* v = s_cbf + tid * D_;
        float s = 0.f;
        #pragma unroll
        for (int d = 0; d < D_; ++d) s = fmaf(v[d], v[d], s);
        s_c2f[tid] = s;
    }
    __syncthreads();

    float xf[BPT1][D_];
    #pragma unroll
    for (int j = 0; j < BPT1; ++j) {
        const int b = btile * BTILE1 + j * TPB + tid;
        const float4* xp = (const float4*)(x + (size_t)b * (C_ * D_) + c * D_);
        const float4 a = xp[0];
        const float4 h = xp[1];
        xf[j][0] = a.x; xf[j][1] = a.y; xf[j][2] = a.z; xf[j][3] = a.w;
        xf[j][4] = h.x; xf[j][5] = h.y; xf[j][6] = h.z; xf[j][7] = h.w;
    }

    float s1[BPT1], s2[BPT1];
    int   k1[BPT1];
    #pragma unroll
    for (int j = 0; j < BPT1; ++j) { s1[j] = 3.4e38f; s2[j] = 3.4e38f; k1[j] = 0; }

    const float4* scb4 = (const float4*)s_cbf;
    #pragma unroll 2
    for (int k = 0; k < K_; ++k) {
        const float4 clo = scb4[k * 2];
        const float4 chi = scb4[k * 2 + 1];
        const float  c2k = s_c2f[k];
        #pragma unroll
        for (int j = 0; j < BPT1; ++j) {
            float dot = xf[j][0] * clo.x;
            dot = fmaf(xf[j][1], clo.y, dot);
            dot = fmaf(xf[j][2], clo.z, dot);
            dot = fmaf(xf[j][3], clo.w, dot);
            dot = fmaf(xf[j][4], chi.x, dot);
            dot = fmaf(xf[j][5], chi.y, dot);
            dot = fmaf(xf[j][6], chi.z, dot);
            dot = fmaf(xf[j][7], chi.w, dot);
            const float score = fmaf(-2.f, dot, c2k);
            // top-2 (s2 uses OLD s1; strict < keeps first-index winner)
            s2[j] = fminf(s2[j], fmaxf(score, s1[j]));
            const bool lt = score < s1[j];
            k1[j] = lt ? k : k1[j];
            s1[j] = lt ? score : s1[j];
        }
    }

    // ---- inline fp64 repair of ambiguous pairs (wave-cooperative) ----
    // Codes sourced from LDS f32 slice; (double)f32 == R2's exact staging, so
    // the repaired argmin is bit-identical to the R2 kernel (absmax 0.0).
    #pragma unroll
    for (int j = 0; j < BPT1; ++j) {
        const bool amb = (s2[j] - s1[j]) <= TAU2;
        unsigned long long mask = __ballot(amb);
        while (mask) {
            const int src = (int)__ffsll((long long)mask) - 1;
            mask &= mask - 1;
            // broadcast owner's x fragment (regs -> all lanes)
            double xd[D_];
            #pragma unroll
            for (int d = 0; d < D_; ++d) xd[d] = (double)__shfl(xf[j][d], src);
            // 4 codes per lane, ascending k within lane
            double best = 1.0e300;
            int    bk   = 0;
            #pragma unroll
            for (int t = 0; t < 4; ++t) {
                const int k = lane * 4 + t;
                const float* cv = s_cbf + k * D_;
                double cd[D_];
                #pragma unroll
                for (int d = 0; d < D_; ++d) cd[d] = (double)cv[d];
                double c2k = 0.0;
                #pragma unroll
                for (int d = 0; d < D_; ++d) c2k = fma(cd[d], cd[d], c2k);
                double dot = xd[0] * cd[0];
                #pragma unroll
                for (int d = 1; d < D_; ++d) dot = fma(xd[d], cd[d], dot);
                const double score = fma(-2.0, dot, c2k);
                if (score < best) { best = score; bk = k; }  // first-min in lane
            }
            // reduce: strictly smaller wins; tie -> keep own (lower lane = lower k)
            #pragma unroll
            for (int off = 32; off >= 1; off >>= 1) {
                const double ob  = __shfl_down(best, off);
                const int    obk = __shfl_down(bk,   off);
                if (ob < best) { best = ob; bk = obk; }
            }
            const int win = __shfl(bk, 0);
            if (lane == src) k1[j] = win;
        }
    }

    #pragma unroll
    for (int j = 0; j < BPT1; ++j) {
        const int b = btile * BTILE1 + j * TPB + tid;
        idx_out[(size_t)b * C_ + c] = k1[j];
    }
}

// ---------------- Pass 2: coalesced streaming writer (unchanged) ----------------
constexpr int GRID3 = 2048;
constexpr int RPB   = NP / GRID3;  // 256 rows per block

__global__ __launch_bounds__(TPB, 4) void vq_write(
    const int*   __restrict__ idx,
    const float* __restrict__ cb,
    float* __restrict__ out_embed,
    float* __restrict__ out_onehot)
{
    const int tid  = threadIdx.x;
    const int lane = tid & 63;
    const int wave = tid >> 6;
    const int blk  = blockIdx.x;

    // one-hot: 64 consecutive rows per wave, 1KB contiguous per store instr
    const int rowbase = blk * RPB + wave * 64;
    const int myk = idx[rowbase + lane];
    const int e0 = lane * 4;
    #pragma unroll 4
    for (int i = 0; i < 64; ++i) {
        const int k = __builtin_amdgcn_readlane(myk, i);
        vf4 v;
        v.x = (k == e0    ) ? 1.f : 0.f;
        v.y = (k == e0 + 1) ? 1.f : 0.f;
        v.z = (k == e0 + 2) ? 1.f : 0.f;
        v.w = (k == e0 + 3) ? 1.f : 0.f;
        vf4* dst = (vf4*)(out_onehot + (size_t)(rowbase + i) * K_) + lane;
        __builtin_nontemporal_store(v, dst);
    }

    // embed: 256 pairs per block = 512 float4, 2 per thread, coalesced
    const size_t pbase = (size_t)blk * RPB;
    #pragma unroll
    for (int i = 0; i < 2; ++i) {
        const int    f    = i * TPB + tid;   // 0..511
        const int    pl   = f >> 1;
        const int    half = f & 1;
        const size_t pair = pbase + pl;
        const int    c    = (int)(pair & (C_ - 1));
        const int    k    = idx[pair];
        const vf4 val = ((const vf4*)(cb + ((size_t)c * K_ + k) * D_))[half];
        __builtin_nontemporal_store(val, (vf4*)(out_embed + pbase * D_) + f);
    }
}

extern "C" void kernel_launch(void* const* d_in, const int* in_sizes, int n_in,
                              void* d_out, int out_size, void* d_ws, size_t ws_size,
                              hipStream_t stream) {
    const float* x  = (const float*)d_in[0];
    const float* cb = (const float*)d_in[1];
    float* out        = (float*)d_out;
    float* out_embed  = out;                          // 4096*1024
    float* out_onehot = out + (size_t)B_ * C_ * D_;   // 4096*128*256
    int*   idx_ws     = (int*)d_ws;                   // 524288 ints = 2 MB

    dim3 grid1(C_, B_ / BTILE1);  // (128, 2) = 256 blocks
    vq_screen_fix<<<grid1, TPB, 0, stream>>>(x, cb, idx_ws);

    vq_write<<<GRID3, TPB, 0, stream>>>(idx_ws, cb, out_embed, out_onehot);
}

// Round 7
// 595.022 us; speedup vs baseline: 1.0212x; 1.0121x over previous
//
#include <hip/hip_runtime.h>

// VQ-VAE codebook quantization — single fused kernel.
// x: (4096, 1024) f32; codebook: (128, 256, 8) f32.
// out = [cw_embed (4096*1024 f32) | one_hot (4096*128*256 f32)].
//
// R6 post-mortem: two dependent dispatches serialize screen compute
// (LDS/VALU, ~40us) and one-hot store drain (HBM, ~95us) although they use
// disjoint pipes. This kernel fuses them: block = (c, 1024 b), 2 passes of
// {BPT=2 fp32 top-2 screen -> inline fp64 repair -> full-wave 1KB row
// stores issued WITHOUT waiting}. Pass-2 compute overlaps pass-1 store
// drain; 2 blocks/CU adds inter-wave overlap. Each one-hot store instr is
// one contiguous 1KB burst (R2's scatter failure was 64 rows per instr;
// row ORDER across instrs doesn't matter to HBM). Embed written cached so
// L2 merges 32B half-lines; one-hot nontemporal. No idx array, no 2nd
// dispatch. Repair numerics byte-identical to R2/R6 (absmax 0.0).

constexpr int B_  = 4096;
constexpr int C_  = 128;
constexpr int K_  = 256;
constexpr int D_  = 8;
constexpr int TPB = 256;

constexpr int   BPT    = 2;                  // pairs per thread per pass
constexpr int   PASSES = 2;
constexpr int   BTILE  = TPB * BPT * PASSES; // 1024 b per block
constexpr float TAU2   = 1.0e-3f;            // ambiguity gap threshold

typedef float vf4 __attribute__((ext_vector_type(4)));

__global__ __launch_bounds__(TPB) void vq_fused(
    const float* __restrict__ x,
    const float* __restrict__ cb,
    float* __restrict__ out_embed,
    float* __restrict__ out_onehot)
{
    __shared__ float s_cbf[K_ * D_];  // 8 KB fp32 codebook slice
    __shared__ float s_c2f[K_];       // 1 KB fp32 ||c_k||^2

    const int c    = blockIdx.x;   // 0..127
    const int bt   = blockIdx.y;   // 0..3
    const int tid  = threadIdx.x;
    const int lane = tid & 63;
    const int wave = tid >> 6;

    // ---- stage codebook slice + c2 (once per block) ----
    {
        const float4* gcb = (const float4*)(cb + (size_t)c * (K_ * D_));
        ((float4*)s_cbf)[tid]       = gcb[tid];
        ((float4*)s_cbf)[tid + TPB] = gcb[tid + TPB];
    }
    __syncthreads();
    {
        const float* v = s_cbf + tid * D_;
        float s = 0.f;
        #pragma unroll
        for (int d = 0; d < D_; ++d) s = fmaf(v[d], v[d], s);
        s_c2f[tid] = s;
    }
    __syncthreads();
    // No barriers after this point: LDS is read-only, k1 lives in registers.

    const float4* scb4 = (const float4*)s_cbf;

    for (int pass = 0; pass < PASSES; ++pass) {
        const int bbase = bt * BTILE + pass * (TPB * BPT);

        // ---- x fragments for this pass ----
        float xf[BPT][D_];
        #pragma unroll
        for (int j = 0; j < BPT; ++j) {
            const int b = bbase + j * TPB + tid;
            const float4* xp = (const float4*)(x + (size_t)b * (C_ * D_) + c * D_);
            const float4 a = xp[0];
            const float4 h = xp[1];
            xf[j][0] = a.x; xf[j][1] = a.y; xf[j][2] = a.z; xf[j][3] = a.w;
            xf[j][4] = h.x; xf[j][5] = h.y; xf[j][6] = h.z; xf[j][7] = h.w;
        }

        // ---- fp32 top-2 screen ----
        float s1[BPT], s2[BPT];
        int   k1[BPT];
        #pragma unroll
        for (int j = 0; j < BPT; ++j) { s1[j] = 3.4e38f; s2[j] = 3.4e38f; k1[j] = 0; }

        #pragma unroll 2
        for (int k = 0; k < K_; ++k) {
            const float4 clo = scb4[k * 2];
            const float4 chi = scb4[k * 2 + 1];
            const float  c2k = s_c2f[k];
            #pragma unroll
            for (int j = 0; j < BPT; ++j) {
                float dot = xf[j][0] * clo.x;
                dot = fmaf(xf[j][1], clo.y, dot);
                dot = fmaf(xf[j][2], clo.z, dot);
                dot = fmaf(xf[j][3], clo.w, dot);
                dot = fmaf(xf[j][4], chi.x, dot);
                dot = fmaf(xf[j][5], chi.y, dot);
                dot = fmaf(xf[j][6], chi.z, dot);
                dot = fmaf(xf[j][7], chi.w, dot);
                const float score = fmaf(-2.f, dot, c2k);
                // top-2 (s2 uses OLD s1; strict < keeps first-index winner)
                s2[j] = fminf(s2[j], fmaxf(score, s1[j]));
                const bool lt = score < s1[j];
                k1[j] = lt ? k : k1[j];
                s1[j] = lt ? score : s1[j];
            }
        }

        // ---- inline fp64 repair of ambiguous pairs (wave-cooperative) ----
        // (double)f32 from LDS == R2's exact staging -> argmin matches np.
        #pragma unroll
        for (int j = 0; j < BPT; ++j) {
            const bool amb = (s2[j] - s1[j]) <= TAU2;
            unsigned long long mask = __ballot(amb);
            while (mask) {
                const int src = (int)__ffsll((long long)mask) - 1;
                mask &= mask - 1;
                double xd[D_];
                #pragma unroll
                for (int d = 0; d < D_; ++d) xd[d] = (double)__shfl(xf[j][d], src);
                double best = 1.0e300;
                int    bk   = 0;
                #pragma unroll
                for (int t = 0; t < 4; ++t) {
                    const int k = lane * 4 + t;      // ascending k within lane
                    const float* cv = s_cbf + k * D_;
                    double cd[D_];
                    #pragma unroll
                    for (int d = 0; d < D_; ++d) cd[d] = (double)cv[d];
                    double c2k = 0.0;
                    #pragma unroll
                    for (int d = 0; d < D_; ++d) c2k = fma(cd[d], cd[d], c2k);
                    double dot = xd[0] * cd[0];
                    #pragma unroll
                    for (int d = 1; d < D_; ++d) dot = fma(xd[d], cd[d], dot);
                    const double score = fma(-2.0, dot, c2k);
                    if (score < best) { best = score; bk = k; }  // first-min
                }
                #pragma unroll
                for (int off = 32; off >= 1; off >>= 1) {
                    const double ob  = __shfl_down(best, off);
                    const int    obk = __shfl_down(bk,   off);
                    if (ob < best) { best = ob; bk = obk; }  // tie -> lower k
                }
                const int win = __shfl(bk, 0);
                if (lane == src) k1[j] = win;
            }
        }

        // ---- writes: issue and move on (stores drain under next pass) ----
        #pragma unroll
        for (int j = 0; j < BPT; ++j) {
            // embed: own pair, 32B from LDS slice (cached stores: L2 merges
            // the two half-lines written by adjacent-c blocks)
            const int    b    = bbase + j * TPB + tid;
            const size_t pair = (size_t)b * C_ + c;
            float4* dst = (float4*)(out_embed + pair * D_);
            dst[0] = ((const float4*)s_cbf)[k1[j] * 2];
            dst[1] = ((const float4*)s_cbf)[k1[j] * 2 + 1];

            // one-hot: this wave writes its 64 lanes' rows, one full-wave
            // 1KB contiguous burst per store instruction.
            const int bw = bbase + j * TPB + wave * 64;
            const int e0 = lane * 4;
            #pragma unroll 8
            for (int i = 0; i < 64; ++i) {
                const int k = __builtin_amdgcn_readlane(k1[j], i);
                vf4 v;
                v.x = (k == e0    ) ? 1.f : 0.f;
                v.y = (k == e0 + 1) ? 1.f : 0.f;
                v.z = (k == e0 + 2) ? 1.f : 0.f;
                v.w = (k == e0 + 3) ? 1.f : 0.f;
                const size_t row = (size_t)(bw + i) * C_ + c;
                vf4* oh = (vf4*)(out_onehot + row * K_) + lane;
                __builtin_nontemporal_store(v, oh);
            }
        }
    }
}

extern "C" void kernel_launch(void* const* d_in, const int* in_sizes, int n_in,
                              void* d_out, int out_size, void* d_ws, size_t ws_size,
                              hipStream_t stream) {
    const float* x  = (const float*)d_in[0];
    const float* cb = (const float*)d_in[1];
    float* out        = (float*)d_out;
    float* out_embed  = out;                          // 4096*1024
    float* out_onehot = out + (size_t)B_ * C_ * D_;   // 4096*128*256

    dim3 grid(C_, B_ / BTILE);  // (128, 4) = 512 blocks, 2 per CU
    vq_fused<<<grid, TPB, 0, stream>>>(x, cb, out_embed, out_onehot);
}

// Round 8
// 582.296 us; speedup vs baseline: 1.0436x; 1.0219x over previous
//
#include <hip/hip_runtime.h>

// VQ-VAE codebook quantization — single fused kernel (R8: cached stores test).
// x: (4096, 1024) f32; codebook: (128, 256, 8) f32.
// out = [cw_embed (4096*1024 f32) | one_hot (4096*128*256 f32)].
//
// R7 post-mortem: compute is fully hidden (fusion moved -7us); the only term
// that can still hold 50-150us is one-hot store throughput. Two deltas vs
// the 6.3TB/s fill kernels: nontemporal stores (bypass L2 write-combining)
// and only 2 blocks/CU of store streams. R8 changes exactly those: regular
// cached stores (full 128B lines per 8 lanes, no RMW) and grid (128,8) =
// 1024 blocks = 4 blocks/CU. Screen + fp64 repair numerics byte-identical
// to R6/R7 (absmax 0.0 across R2-R7).

constexpr int B_  = 4096;
constexpr int C_  = 128;
constexpr int K_  = 256;
constexpr int D_  = 8;
constexpr int TPB = 256;

constexpr int   BPT   = 2;           // pairs per thread
constexpr int   BTILE = TPB * BPT;   // 512 b per block
constexpr float TAU2  = 1.0e-3f;     // ambiguity gap threshold

typedef float vf4 __attribute__((ext_vector_type(4)));

__global__ __launch_bounds__(TPB) void vq_fused(
    const float* __restrict__ x,
    const float* __restrict__ cb,
    float* __restrict__ out_embed,
    float* __restrict__ out_onehot)
{
    __shared__ float s_cbf[K_ * D_];  // 8 KB fp32 codebook slice
    __shared__ float s_c2f[K_];       // 1 KB fp32 ||c_k||^2

    const int c    = blockIdx.x;   // 0..127
    const int bt   = blockIdx.y;   // 0..7
    const int tid  = threadIdx.x;
    const int lane = tid & 63;
    const int wave = tid >> 6;

    // ---- stage codebook slice + c2 ----
    {
        const float4* gcb = (const float4*)(cb + (size_t)c * (K_ * D_));
        ((float4*)s_cbf)[tid]       = gcb[tid];
        ((float4*)s_cbf)[tid + TPB] = gcb[tid + TPB];
    }
    __syncthreads();
    {
        const float* v = s_cbf + tid * D_;
        float s = 0.f;
        #pragma unroll
        for (int d = 0; d < D_; ++d) s = fmaf(v[d], v[d], s);
        s_c2f[tid] = s;
    }
    __syncthreads();
    // LDS read-only below; k1 lives in registers — no more barriers.

    const float4* scb4 = (const float4*)s_cbf;
    const int bbase = bt * BTILE;

    // ---- x fragments ----
    float xf[BPT][D_];
    #pragma unroll
    for (int j = 0; j < BPT; ++j) {
        const int b = bbase + j * TPB + tid;
        const float4* xp = (const float4*)(x + (size_t)b * (C_ * D_) + c * D_);
        const float4 a = xp[0];
        const float4 h = xp[1];
        xf[j][0] = a.x; xf[j][1] = a.y; xf[j][2] = a.z; xf[j][3] = a.w;
        xf[j][4] = h.x; xf[j][5] = h.y; xf[j][6] = h.z; xf[j][7] = h.w;
    }

    // ---- fp32 top-2 screen ----
    float s1[BPT], s2[BPT];
    int   k1[BPT];
    #pragma unroll
    for (int j = 0; j < BPT; ++j) { s1[j] = 3.4e38f; s2[j] = 3.4e38f; k1[j] = 0; }

    #pragma unroll 2
    for (int k = 0; k < K_; ++k) {
        const float4 clo = scb4[k * 2];
        const float4 chi = scb4[k * 2 + 1];
        const float  c2k = s_c2f[k];
        #pragma unroll
        for (int j = 0; j < BPT; ++j) {
            float dot = xf[j][0] * clo.x;
            dot = fmaf(xf[j][1], clo.y, dot);
            dot = fmaf(xf[j][2], clo.z, dot);
            dot = fmaf(xf[j][3], clo.w, dot);
            dot = fmaf(xf[j][4], chi.x, dot);
            dot = fmaf(xf[j][5], chi.y, dot);
            dot = fmaf(xf[j][6], chi.z, dot);
            dot = fmaf(xf[j][7], chi.w, dot);
            const float score = fmaf(-2.f, dot, c2k);
            // top-2 (s2 uses OLD s1; strict < keeps first-index winner)
            s2[j] = fminf(s2[j], fmaxf(score, s1[j]));
            const bool lt = score < s1[j];
            k1[j] = lt ? k : k1[j];
            s1[j] = lt ? score : s1[j];
        }
    }

    // ---- inline fp64 repair of ambiguous pairs (wave-cooperative) ----
    // (double)f32 from LDS == R2's exact staging -> argmin matches np.
    #pragma unroll
    for (int j = 0; j < BPT; ++j) {
        const bool amb = (s2[j] - s1[j]) <= TAU2;
        unsigned long long mask = __ballot(amb);
        while (mask) {
            const int src = (int)__ffsll((long long)mask) - 1;
            mask &= mask - 1;
            double xd[D_];
            #pragma unroll
            for (int d = 0; d < D_; ++d) xd[d] = (double)__shfl(xf[j][d], src);
            double best = 1.0e300;
            int    bk   = 0;
            #pragma unroll
            for (int t = 0; t < 4; ++t) {
                const int k = lane * 4 + t;      // ascending k within lane
                const float* cv = s_cbf + k * D_;
                double cd[D_];
                #pragma unroll
                for (int d = 0; d < D_; ++d) cd[d] = (double)cv[d];
                double c2k = 0.0;
                #pragma unroll
                for (int d = 0; d < D_; ++d) c2k = fma(cd[d], cd[d], c2k);
                double dot = xd[0] * cd[0];
                #pragma unroll
                for (int d = 1; d < D_; ++d) dot = fma(xd[d], cd[d], dot);
                const double score = fma(-2.0, dot, c2k);
                if (score < best) { best = score; bk = k; }  // first-min
            }
            #pragma unroll
            for (int off = 32; off >= 1; off >>= 1) {
                const double ob  = __shfl_down(best, off);
                const int    obk = __shfl_down(bk,   off);
                if (ob < best) { best = ob; bk = obk; }  // tie -> lower k
            }
            const int win = __shfl(bk, 0);
            if (lane == src) k1[j] = win;
        }
    }

    // ---- writes (cached; full lines per 8 lanes, no RMW on one-hot) ----
    #pragma unroll
    for (int j = 0; j < BPT; ++j) {
        // embed: own pair, 32B from LDS slice; L2 merges half-lines across
        // adjacent-c blocks (cached stores).
        const int    b    = bbase + j * TPB + tid;
        const size_t pair = (size_t)b * C_ + c;
        float4* dst = (float4*)(out_embed + pair * D_);
        dst[0] = ((const float4*)s_cbf)[k1[j] * 2];
        dst[1] = ((const float4*)s_cbf)[k1[j] * 2 + 1];

        // one-hot: wave writes its 64 lanes' rows; each store instruction is
        // one contiguous 1KB burst (16 full lines).
        const int bw = bbase + j * TPB + wave * 64;
        const int e0 = lane * 4;
        #pragma unroll 8
        for (int i = 0; i < 64; ++i) {
            const int k = __builtin_amdgcn_readlane(k1[j], i);
            vf4 v;
            v.x = (k == e0    ) ? 1.f : 0.f;
            v.y = (k == e0 + 1) ? 1.f : 0.f;
            v.z = (k == e0 + 2) ? 1.f : 0.f;
            v.w = (k == e0 + 3) ? 1.f : 0.f;
            const size_t row = (size_t)(bw + i) * C_ + c;
            ((vf4*)(out_onehot + row * K_))[lane] = v;
        }
    }
}

extern "C" void kernel_launch(void* const* d_in, const int* in_sizes, int n_in,
                              void* d_out, int out_size, void* d_ws, size_t ws_size,
                              hipStream_t stream) {
    const float* x  = (const float*)d_in[0];
    const float* cb = (const float*)d_in[1];
    float* out        = (float*)d_out;
    float* out_embed  = out;                          // 4096*1024
    float* out_onehot = out + (size_t)B_ * C_ * D_;   // 4096*128*256

    dim3 grid(C_, B_ / BTILE);  // (128, 8) = 1024 blocks, 4 per CU
    vq_fused<<<grid, TPB, 0, stream>>>(x, cb, out_embed, out_onehot);
}